// Round 10
// baseline (330.462 us; speedup 1.0000x reference)
//
#include <hip/hip_runtime.h>

#define N_NODES 50000
#define E_EDGES 200000
#define R_REL 3
#define D_IN 128
#define D_HID 128
#define D_OUT 64
#define N_SCAN (R_REL * N_NODES)          // 150000
#define BCAP 16
#define OVCAP 4096

typedef __attribute__((ext_vector_type(8))) short bf16x8;
typedef __attribute__((ext_vector_type(4))) float f32x4;

__device__ inline unsigned short f2bf(float v) {
    union { float f; unsigned int u; } x; x.f = v;
    unsigned int r = x.u + 0x7fffu + ((x.u >> 16) & 1u);
    return (unsigned short)(r >> 16);
}
__device__ inline float bf2f(unsigned short h) {
    union { unsigned int u; float f; } x; x.u = ((unsigned int)h) << 16; return x.f;
}
__device__ inline float bf_lo(unsigned int p) {
    union { unsigned int u; float f; } x; x.u = p << 16; return x.f;
}
__device__ inline float bf_hi(unsigned int p) {
    union { unsigned int u; float f; } x; x.u = p & 0xffff0000u; return x.f;
}

// ---------------- zero counters ----------------
__global__ __launch_bounds__(256) void k_zero_i32(int* __restrict__ p, int n) {
    int i = blockIdx.x * 256 + threadIdx.x;
    if (i < n) p[i] = 0;
}

// ---------------- fused count/bucket + prep, role-split blocks ----------------
__global__ __launch_bounds__(256) void k_count_prep(const int* __restrict__ src,
                                                    const int* __restrict__ dst,
                                                    const float* __restrict__ x,
                                                    const float* __restrict__ W1,
                                                    const float* __restrict__ W2,
                                                    const float* __restrict__ b1,
                                                    int* __restrict__ deg_out,
                                                    int* __restrict__ cnt_in,
                                                    int* __restrict__ ov_cnt,
                                                    uint2* __restrict__ ovlist,
                                                    int* __restrict__ bucket,
                                                    unsigned int* __restrict__ xb,
                                                    unsigned short* __restrict__ w1t_h,
                                                    unsigned short* __restrict__ w1t_l,
                                                    unsigned short* __restrict__ w2t_h,
                                                    unsigned short* __restrict__ w2t_l,
                                                    float* __restrict__ bsum) {
    int g = blockIdx.x / 5;
    int m = blockIdx.x % 5;
    int t = threadIdx.x;
    if (m < 3) {
        // ---- edge path: count + bucket scatter ----
        int eb = g * 3 + m;
        int i = eb * 256 + t;
        if (i >= R_REL * E_EDGES) return;
        int r = i / E_EDGES;
        int s = src[i];
        int d = dst[i];
        atomicAdd(&deg_out[r * N_NODES + s], 1);
        int bin = r * N_NODES + d;
        int pos = atomicAdd(&cnt_in[bin], 1);
        if (pos < BCAP) {
            bucket[bin * BCAP + pos] = s;
        } else {
            int oi = atomicAdd(ov_cnt, 1);
            if (oi < OVCAP) {
                uint2 e;
                e.x = (unsigned int)bin;
                e.y = (unsigned int)s;
                ovlist[oi] = e;
            }
        }
    } else {
        // ---- streaming prep path (coalesced: 4 lane-consecutive passes) ----
        int pb = g * 2 + (m - 3);
        int qbase = pb * 1024;
#pragma unroll
        for (int k = 0; k < 4; k++) {
            int q = qbase + k * 256 + t;
            if (q < N_NODES * 32) {
                float4 v = ((const float4*)x)[q];
                uint2 u;
                u.x = ((unsigned int)f2bf(v.y) << 16) | f2bf(v.x);
                u.y = ((unsigned int)f2bf(v.w) << 16) | f2bf(v.z);
                ((uint2*)xb)[q] = u;
            }
        }
        int i = pb * 256 + t;
        if (i < R_REL * D_IN * D_HID) {  // 49152
            int r = i >> 14;
            int kk = (i >> 7) & 127;
            int c = i & 127;
            float v = W1[i];
            unsigned short h = f2bf(v);
            unsigned short l = f2bf(v - bf2f(h));
            int o = r * 16384 + c * 128 + kk;
            w1t_h[o] = h;
            w1t_l[o] = l;
        }
        if (i < R_REL * D_HID * D_OUT) {  // 24576
            int r = i >> 13;
            int kk = (i >> 6) & 127;
            int cl = i & 63;
            float v = W2[i];
            unsigned short h = f2bf(v);
            unsigned short l = f2bf(v - bf2f(h));
            int o = (r * 64 + cl) * 128 + kk;
            w2t_h[o] = h;
            w2t_l[o] = l;
        }
        if (i < 128) bsum[i] = b1[i] + b1[128 + i] + b1[256 + i];
    }
}

// ---------------- norms from counts ----------------
__global__ __launch_bounds__(256) void k_rednorm(const int* __restrict__ deg_out,
                                                 const int* __restrict__ cnt_in,
                                                 float* __restrict__ norm_out,
                                                 float* __restrict__ norm_in) {
    int b = blockIdx.x * 256 + threadIdx.x;
    if (b >= N_SCAN) return;
    int o = deg_out[b];
    int d = cnt_in[b];
    norm_out[b] = rsqrtf((float)(o > 1 ? o : 1));
    norm_in[b] = rsqrtf((float)(d > 1 ? d : 1));
}

// ---------------- layer-1 aggregation: wave = (node, relation, feat-half) ----------------
// 128B half-row gathers (lane = 1 bf16 feat); grid.z slowest -> half 0 mostly
// completes before half 1 starts, shrinking the instantaneous gather working set
// to ~6.4MB for better L2 hit rate (locality heuristic only, order-independent).
__global__ __launch_bounds__(256) void k_aggall(const int* __restrict__ cnt_in,
                                                const int* __restrict__ bucket,
                                                const float* __restrict__ norm_out,
                                                const float* __restrict__ norm_in,
                                                const int* __restrict__ ov_cnt,
                                                const uint2* __restrict__ ovlist,
                                                const unsigned short* __restrict__ xb,
                                                unsigned short* __restrict__ aggh) {
    int w = (blockIdx.x * 256 + threadIdx.x) >> 6;
    if (w >= N_NODES) return;
    int r = blockIdx.y;
    int h = blockIdx.z;
    int lane = threadIdx.x & 63;
    const unsigned short* tab = xb + h * 64 + lane;   // row stride 128 ushorts
    const float* nout = norm_out + r * N_NODES;
    int bin = r * N_NODES + w;
    int n = cnt_in[bin];
    int nn = n < BCAP ? n : BCAP;
    const uint4* bp = (const uint4*)(bucket + bin * BCAP);
    uint4 q0 = bp[0], q1 = bp[1], q2 = bp[2], q3 = bp[3];
    unsigned int sl[BCAP] = {q0.x, q0.y, q0.z, q0.w, q1.x, q1.y, q1.z, q1.w,
                             q2.x, q2.y, q2.z, q2.w, q3.x, q3.y, q3.z, q3.w};
    float c[BCAP];
    unsigned short pv[BCAP];
    // phase 1: issue all gathers
#pragma unroll
    for (int j = 0; j < BCAP; j++) {
        if (j < nn) {
            c[j] = nout[sl[j]];
            pv[j] = tab[sl[j] * 128];
        }
    }
    // phase 2: consume
    float a = 0.f;
#pragma unroll
    for (int j = 0; j < BCAP; j++) {
        if (j < nn) a += c[j] * bf2f(pv[j]);
    }
    int oc = *ov_cnt;
    if (oc > 0) {
        if (oc > OVCAP) oc = OVCAP;
        for (int k = 0; k < oc; k++) {
            uint2 e = ovlist[k];
            if ((int)e.x == bin) a += nout[e.y] * bf2f(tab[e.y * 128]);
        }
    }
    aggh[bin * 128 + h * 64 + lane] = f2bf(a * norm_in[bin]);
}

// ---------------- layer-1 GEMM: h1 = relu([A0|A1|A2](N,384) @ W1cat(384,128) + bsum) ----------------
__global__ __launch_bounds__(256) void k_mm1f(const unsigned short* __restrict__ aggh,
                                              const unsigned short* __restrict__ wt_h,
                                              const unsigned short* __restrict__ wt_l,
                                              const float* __restrict__ bsum,
                                              unsigned short* __restrict__ h1h,
                                              unsigned short* __restrict__ h1l,
                                              int M) {
    __shared__ short sA[2048];                 // [4 kg][64 row][8]
    __shared__ short sWh[4096], sWl[4096];     // [4 kg][128 col][8]
    int t = threadIdx.x;
    int row0 = blockIdx.x * 64;
    int wid = t >> 6;
    int lane = t & 63;
    int lr = lane & 15;
    int lkg = lane >> 4;
    int wr = (wid & 1) * 32;
    int wc = (wid >> 1) * 64;

    f32x4 acc[2][4];
#pragma unroll
    for (int i = 0; i < 2; i++)
#pragma unroll
        for (int j = 0; j < 4; j++) acc[i][j] = (f32x4)(0.f);

    int arow = t >> 2;       // 0..63
    int akg = t & 3;         // 0..3

    for (int k0 = 0; k0 < 384; k0 += 32) {
        int rr = k0 >> 7;
        int kk = k0 & 127;
        {
            int gr = row0 + arow;
            int cidx = akg * 64 + arow;
            if (gr < M)
                *(bf16x8*)&sA[cidx * 8] =
                    *(const bf16x8*)&aggh[(rr * N_NODES + gr) * 128 + kk + akg * 8];
            else
                *(bf16x8*)&sA[cidx * 8] = (bf16x8)(short)0;
        }
#pragma unroll
        for (int itr = 0; itr < 2; itr++) {
            int cc = t + itr * 256;       // 0..511
            int col = cc >> 2;            // 0..127
            int kg = cc & 3;
            int go = rr * 16384 + col * 128 + kk + kg * 8;
            int cidx = kg * 128 + col;
            *(bf16x8*)&sWh[cidx * 8] = *(const bf16x8*)&wt_h[go];
            *(bf16x8*)&sWl[cidx * 8] = *(const bf16x8*)&wt_l[go];
        }
        __syncthreads();
        bf16x8 a[2], bh[4], bl[4];
#pragma unroll
        for (int i = 0; i < 2; i++) {
            int cidx = lkg * 64 + wr + i * 16 + lr;
            a[i] = *(const bf16x8*)&sA[cidx * 8];
        }
#pragma unroll
        for (int j = 0; j < 4; j++) {
            int cidx = lkg * 128 + wc + j * 16 + lr;
            bh[j] = *(const bf16x8*)&sWh[cidx * 8];
            bl[j] = *(const bf16x8*)&sWl[cidx * 8];
        }
#pragma unroll
        for (int i = 0; i < 2; i++)
#pragma unroll
            for (int j = 0; j < 4; j++) {
                acc[i][j] = __builtin_amdgcn_mfma_f32_16x16x32_bf16(a[i], bh[j], acc[i][j], 0, 0, 0);
                acc[i][j] = __builtin_amdgcn_mfma_f32_16x16x32_bf16(a[i], bl[j], acc[i][j], 0, 0, 0);
            }
        __syncthreads();
    }
#pragma unroll
    for (int i = 0; i < 2; i++)
#pragma unroll
        for (int q = 0; q < 4; q++) {
            int gr = row0 + wr + i * 16 + lkg * 4 + q;
            if (gr >= M) continue;
#pragma unroll
            for (int j = 0; j < 4; j++) {
                int gc = wc + j * 16 + lr;
                float u = fmaxf(acc[i][j][q] + bsum[gc], 0.f);
                unsigned short h = f2bf(u);
                h1h[gr * 128 + gc] = h;
                h1l[gr * 128 + gc] = f2bf(u - bf2f(h));
            }
        }
}

// ---------------- MFMA split-bf16 GEMM, layer 2 (bf16 out, plane-major, norm folded) ----------------
__global__ __launch_bounds__(256) void k_mm2(const unsigned short* __restrict__ h1h,
                                             const unsigned short* __restrict__ h1l,
                                             const unsigned short* __restrict__ wt_h,
                                             const unsigned short* __restrict__ wt_l,
                                             const float* __restrict__ norm_out,
                                             unsigned short* __restrict__ xwb2, int M) {
    __shared__ short sAh[2048], sAl[2048];
    __shared__ short sWh[6144], sWl[6144];
    int t = threadIdx.x;
    int row0 = blockIdx.x * 64;
    int wid = t >> 6;
    int lane = t & 63;
    int lr = lane & 15;
    int lkg = lane >> 4;
    int wr = (wid & 1) * 32;
    int wc = (wid >> 1) * 96;

    f32x4 acc[2][6];
#pragma unroll
    for (int i = 0; i < 2; i++)
#pragma unroll
        for (int j = 0; j < 6; j++) acc[i][j] = (f32x4)(0.f);

    int arow = t >> 2;
    int akg = t & 3;

    for (int k0 = 0; k0 < 128; k0 += 32) {
        {
            int gr = row0 + arow;
            int cidx = akg * 64 + arow;
            if (gr < M) {
                int go = gr * 128 + k0 + akg * 8;
                *(bf16x8*)&sAh[cidx * 8] = *(const bf16x8*)&h1h[go];
                *(bf16x8*)&sAl[cidx * 8] = *(const bf16x8*)&h1l[go];
            } else {
                *(bf16x8*)&sAh[cidx * 8] = (bf16x8)(short)0;
                *(bf16x8*)&sAl[cidx * 8] = (bf16x8)(short)0;
            }
        }
#pragma unroll
        for (int itr = 0; itr < 3; itr++) {
            int cc = t + itr * 256;       // 0..767
            int col = cc >> 2;
            int kg = cc & 3;
            int go = col * 128 + k0 + kg * 8;
            int cidx = kg * 192 + col;
            *(bf16x8*)&sWh[cidx * 8] = *(const bf16x8*)&wt_h[go];
            *(bf16x8*)&sWl[cidx * 8] = *(const bf16x8*)&wt_l[go];
        }
        __syncthreads();
        bf16x8 ah[2], al[2];
#pragma unroll
        for (int i = 0; i < 2; i++) {
            int cidx = lkg * 64 + wr + i * 16 + lr;
            ah[i] = *(const bf16x8*)&sAh[cidx * 8];
            al[i] = *(const bf16x8*)&sAl[cidx * 8];
        }
#pragma unroll
        for (int j = 0; j < 6; j++) {
            int cidx = lkg * 192 + wc + j * 16 + lr;
            bf16x8 bh = *(const bf16x8*)&sWh[cidx * 8];
            bf16x8 bl = *(const bf16x8*)&sWl[cidx * 8];
#pragma unroll
            for (int i = 0; i < 2; i++) {
                acc[i][j] = __builtin_amdgcn_mfma_f32_16x16x32_bf16(ah[i], bh, acc[i][j], 0, 0, 0);
                acc[i][j] = __builtin_amdgcn_mfma_f32_16x16x32_bf16(ah[i], bl, acc[i][j], 0, 0, 0);
                acc[i][j] = __builtin_amdgcn_mfma_f32_16x16x32_bf16(al[i], bh, acc[i][j], 0, 0, 0);
            }
        }
        __syncthreads();
    }
#pragma unroll
    for (int i = 0; i < 2; i++)
#pragma unroll
        for (int q = 0; q < 4; q++) {
            int gr = row0 + wr + i * 16 + lkg * 4 + q;
            if (gr >= M) continue;
#pragma unroll
            for (int j = 0; j < 6; j++) {
                int gc = wc + j * 16 + lr;
                int rr = gc >> 6;
                int cl = gc & 63;
                float sc = norm_out[rr * N_NODES + gr];
                // plane-major: [r][node][64]
                xwb2[rr * (N_NODES * 64) + gr * 64 + cl] = f2bf(acc[i][j][q] * sc);
            }
        }
}

// ---------------- fused layer-2 aggregation (plane-major gather, staged) ----------------
__global__ __launch_bounds__(256) void k_agg64f(const int* __restrict__ cnt_in,
                                                const int* __restrict__ bucket,
                                                const float* __restrict__ norm_in,
                                                const int* __restrict__ ov_cnt,
                                                const uint2* __restrict__ ovlist,
                                                const unsigned short* __restrict__ xwb,
                                                const float* __restrict__ b2,
                                                unsigned short* __restrict__ h2b) {
    int w = (blockIdx.x * 256 + threadIdx.x) >> 6;
    if (w >= N_NODES) return;
    int lane = threadIdx.x & 63;
    float acc = b2[lane] + b2[64 + lane] + b2[128 + lane];
    int oc = *ov_cnt;
    if (oc > OVCAP) oc = OVCAP;
#pragma unroll
    for (int r = 0; r < R_REL; r++) {
        const unsigned short* tab = xwb + r * (N_NODES * 64) + lane;  // plane-major
        int bin = r * N_NODES + w;
        int n = cnt_in[bin];
        const uint4* bp = (const uint4*)(bucket + bin * BCAP);
        uint4 q0 = bp[0], q1 = bp[1], q2 = bp[2], q3 = bp[3];
        unsigned int sl[BCAP] = {q0.x, q0.y, q0.z, q0.w, q1.x, q1.y, q1.z, q1.w,
                                 q2.x, q2.y, q2.z, q2.w, q3.x, q3.y, q3.z, q3.w};
        int nn = n < BCAP ? n : BCAP;
        unsigned short pv[BCAP];
        // phase 1: issue all gathers
#pragma unroll
        for (int j = 0; j < BCAP; j++) {
            if (j < nn) pv[j] = tab[sl[j] * 64];
        }
        // phase 2: consume
        float a = 0.f;
#pragma unroll
        for (int j = 0; j < BCAP; j++) {
            if (j < nn) a += bf2f(pv[j]);
        }
        if (oc > 0) {
            for (int k = 0; k < oc; k++) {
                uint2 e = ovlist[k];
                if ((int)e.x == bin) a += bf2f(tab[e.y * 64]);
            }
        }
        acc += norm_in[bin] * a;
    }
    h2b[w * 64 + lane] = f2bf(acc);
}

// ---------------- predictor (bf16 h2) ----------------
__global__ __launch_bounds__(256) void k_predict(const int* __restrict__ sa,
                                                 const int* __restrict__ sb,
                                                 const int* __restrict__ na,
                                                 const int* __restrict__ nb,
                                                 const unsigned short* __restrict__ h2b,
                                                 float* __restrict__ out) {
    int tid = blockIdx.x * 256 + threadIdx.x;
    int p = tid >> 4;
    if (p >= 2 * E_EDGES) return;
    int lane = tid & 15;
    int ia, ib;
    if (p < E_EDGES) { ia = sa[p]; ib = sb[p]; }
    else             { ia = na[p - E_EDGES]; ib = nb[p - E_EDGES]; }
    uint2 ua = *(const uint2*)&h2b[ia * 64 + lane * 4];
    uint2 ub = *(const uint2*)&h2b[ib * 64 + lane * 4];
    float d = bf_lo(ua.x) * bf_lo(ub.x) + bf_hi(ua.x) * bf_hi(ub.x)
            + bf_lo(ua.y) * bf_lo(ub.y) + bf_hi(ua.y) * bf_hi(ub.y);
    d += __shfl_xor(d, 1);
    d += __shfl_xor(d, 2);
    d += __shfl_xor(d, 4);
    d += __shfl_xor(d, 8);
    if (lane == 0) out[p] = d;
}

// ---------------- launch ----------------

extern "C" void kernel_launch(void* const* d_in, const int* in_sizes, int n_in,
                              void* d_out, int out_size, void* d_ws, size_t ws_size,
                              hipStream_t stream) {
    (void)in_sizes; (void)n_in; (void)out_size; (void)ws_size;
    const float* x       = (const float*)d_in[0];
    const int*   src     = (const int*)d_in[1];
    const int*   dst     = (const int*)d_in[2];
    const int*   neg_src = (const int*)d_in[3];
    const int*   neg_dst = (const int*)d_in[4];
    const float* W1      = (const float*)d_in[5];
    const float* b1      = (const float*)d_in[6];
    const float* W2      = (const float*)d_in[7];
    const float* b2      = (const float*)d_in[8];
    float* out = (float*)d_out;
    float* ws  = (float*)d_ws;

    // float-offset layout (total 19,082,064 floats = 76.3 MB; 96.8 MB proven):
    // 0        : norm_out [150000]   150000: norm_in [150000]
    // 300000   : deg_out int [150000]  450000: cnt_in [150000]  600000: ov_cnt [16]
    // 600016   : ovlist uint2 [4096] = 8192 ints
    // 608208   : bucket int [2.4M]
    // 3008208  : w1t_h [24576] 3032784: w1t_l [24576] 3057360: w2t_h [12288]
    // 3069648  : w2t_l [12288] 3081936: bsum [128]
    // 3082064  : aggh bf16 [3 planes, 9.6M floats]   (alias: xwb2 plane-major 4.8Mf late)
    // 12682064 : h1h [3.2M]                          (alias: h2b 1.6M floats late)
    // 15882064 : h1l [3.2M]                          (alias: xb 3.2M early)
    float* norm_out = ws;
    float* norm_in  = ws + N_SCAN;
    int*   deg_out  = (int*)(ws + 300000);
    int*   cnt_in   = (int*)(ws + 450000);
    int*   ov_cnt   = (int*)(ws + 600000);
    uint2* ovlist   = (uint2*)(ws + 600016);
    int*   bucket   = (int*)(ws + 608208);
    unsigned short* w1t_h = (unsigned short*)(ws + 3008208);
    unsigned short* w1t_l = (unsigned short*)(ws + 3032784);
    unsigned short* w2t_h = (unsigned short*)(ws + 3057360);
    unsigned short* w2t_l = (unsigned short*)(ws + 3069648);
    float* bsum     = ws + 3081936;
    unsigned short* aggh = (unsigned short*)(ws + 3082064);
    unsigned short* xwb2 = (unsigned short*)(ws + 3082064);
    unsigned short* h1h  = (unsigned short*)(ws + 12682064);
    unsigned short* h2b  = (unsigned short*)(ws + 12682064);
    unsigned short* h1l  = (unsigned short*)(ws + 15882064);
    unsigned int*   xb   = (unsigned int*)(ws + 15882064);

    const int NB_WAVE = (N_NODES * 64 + 255) / 256;      // 12500
    const int NB_MM   = (N_NODES + 63) / 64;             // 782

    // zero counters (deg_out, cnt_in, ov_cnt contiguous)
    k_zero_i32<<<(300016 + 255) / 256, 256, 0, stream>>>(deg_out, 300016);
    // fused count + bucket-scatter + prep (role-split, 782 groups of 5 blocks)
    k_count_prep<<<782 * 5, 256, 0, stream>>>(src, dst, x, W1, W2, b1,
                                              deg_out, cnt_in, ov_cnt, ovlist, bucket,
                                              xb, w1t_h, w1t_l, w2t_h, w2t_l, bsum);
    k_rednorm<<<(N_SCAN + 255) / 256, 256, 0, stream>>>(deg_out, cnt_in, norm_out, norm_in);

    // ---- layer 1: aggregation (wave = node x rel x feat-half) + one K=384 GEMM ----
    dim3 gagg(NB_WAVE, R_REL, 2);
    k_aggall<<<gagg, 256, 0, stream>>>(cnt_in, bucket, norm_out, norm_in,
                                       ov_cnt, ovlist, (const unsigned short*)xb, aggh);
    k_mm1f<<<NB_MM, 256, 0, stream>>>(aggh, w1t_h, w1t_l, bsum, h1h, h1l, N_NODES);

    // ---- layer 2: GEMM [N,128]@[128,192] -> bf16 plane-major, then aggregation ----
    k_mm2<<<NB_MM, 256, 0, stream>>>(h1h, h1l, w2t_h, w2t_l, norm_out, xwb2, N_NODES);
    k_agg64f<<<NB_WAVE, 256, 0, stream>>>(cnt_in, bucket, norm_in, ov_cnt, ovlist,
                                          xwb2, b2, h2b);

    // ---- predictor ----
    k_predict<<<(2 * E_EDGES * 16 + 255) / 256, 256, 0, stream>>>(
        src, dst, neg_src, neg_dst, h2b, out);
}

// Round 11
// 279.876 us; speedup vs baseline: 1.1807x; 1.1807x over previous
//
#include <hip/hip_runtime.h>

#define N_NODES 50000
#define E_EDGES 200000
#define R_REL 3
#define D_IN 128
#define D_HID 128
#define D_OUT 64
#define N_SCAN (R_REL * N_NODES)          // 150000
#define BCAP 16
#define OVCAP 4096

typedef __attribute__((ext_vector_type(8))) short bf16x8;
typedef __attribute__((ext_vector_type(4))) float f32x4;

__device__ inline unsigned short f2bf(float v) {
    union { float f; unsigned int u; } x; x.f = v;
    unsigned int r = x.u + 0x7fffu + ((x.u >> 16) & 1u);
    return (unsigned short)(r >> 16);
}
__device__ inline float bf2f(unsigned short h) {
    union { unsigned int u; float f; } x; x.u = ((unsigned int)h) << 16; return x.f;
}
__device__ inline float bf_lo(unsigned int p) {
    union { unsigned int u; float f; } x; x.u = p << 16; return x.f;
}
__device__ inline float bf_hi(unsigned int p) {
    union { unsigned int u; float f; } x; x.u = p & 0xffff0000u; return x.f;
}

// ---------------- fused count/bucket + prep, role-split blocks ----------------
__global__ __launch_bounds__(256) void k_count_prep(const int* __restrict__ src,
                                                    const int* __restrict__ dst,
                                                    const float* __restrict__ x,
                                                    const float* __restrict__ W1,
                                                    const float* __restrict__ W2,
                                                    const float* __restrict__ b1,
                                                    int* __restrict__ deg_out,
                                                    int* __restrict__ cnt_in,
                                                    int* __restrict__ ov_cnt,
                                                    uint2* __restrict__ ovlist,
                                                    int* __restrict__ bucket,
                                                    unsigned int* __restrict__ xb,
                                                    unsigned short* __restrict__ w1t_h,
                                                    unsigned short* __restrict__ w1t_l,
                                                    unsigned short* __restrict__ w2t_h,
                                                    unsigned short* __restrict__ w2t_l,
                                                    float* __restrict__ bsum) {
    int g = blockIdx.x / 5;
    int m = blockIdx.x % 5;
    int t = threadIdx.x;
    if (m < 3) {
        // ---- edge path: count + bucket scatter ----
        int eb = g * 3 + m;
        int i = eb * 256 + t;
        if (i >= R_REL * E_EDGES) return;
        int r = i / E_EDGES;
        int s = src[i];
        int d = dst[i];
        atomicAdd(&deg_out[r * N_NODES + s], 1);
        int bin = r * N_NODES + d;
        int pos = atomicAdd(&cnt_in[bin], 1);
        if (pos < BCAP) {
            bucket[bin * BCAP + pos] = s;
        } else {
            int oi = atomicAdd(ov_cnt, 1);
            if (oi < OVCAP) {
                uint2 e;
                e.x = (unsigned int)bin;
                e.y = (unsigned int)s;
                ovlist[oi] = e;
            }
        }
    } else {
        // ---- streaming prep path (coalesced: 4 lane-consecutive passes) ----
        int pb = g * 2 + (m - 3);
        int qbase = pb * 1024;
#pragma unroll
        for (int k = 0; k < 4; k++) {
            int q = qbase + k * 256 + t;
            if (q < N_NODES * 32) {
                float4 v = ((const float4*)x)[q];
                uint2 u;
                u.x = ((unsigned int)f2bf(v.y) << 16) | f2bf(v.x);
                u.y = ((unsigned int)f2bf(v.w) << 16) | f2bf(v.z);
                ((uint2*)xb)[q] = u;
            }
        }
        int i = pb * 256 + t;
        if (i < R_REL * D_IN * D_HID) {  // 49152
            int r = i >> 14;
            int kk = (i >> 7) & 127;
            int c = i & 127;
            float v = W1[i];
            unsigned short h = f2bf(v);
            unsigned short l = f2bf(v - bf2f(h));
            int o = r * 16384 + c * 128 + kk;
            w1t_h[o] = h;
            w1t_l[o] = l;
        }
        if (i < R_REL * D_HID * D_OUT) {  // 24576
            int r = i >> 13;
            int kk = (i >> 6) & 127;
            int cl = i & 63;
            float v = W2[i];
            unsigned short h = f2bf(v);
            unsigned short l = f2bf(v - bf2f(h));
            int o = (r * 64 + cl) * 128 + kk;
            w2t_h[o] = h;
            w2t_l[o] = l;
        }
        if (i < 128) bsum[i] = b1[i] + b1[128 + i] + b1[256 + i];
    }
}

// ---------------- norms from counts ----------------
__global__ __launch_bounds__(256) void k_rednorm(const int* __restrict__ deg_out,
                                                 const int* __restrict__ cnt_in,
                                                 float* __restrict__ norm_out,
                                                 float* __restrict__ norm_in) {
    int b = blockIdx.x * 256 + threadIdx.x;
    if (b >= N_SCAN) return;
    int o = deg_out[b];
    int d = cnt_in[b];
    norm_out[b] = rsqrtf((float)(o > 1 ? o : 1));
    norm_in[b] = rsqrtf((float)(d > 1 ? d : 1));
}

// ---------------- layer-1 aggregation: one wave per node, 3 relations ----------------
// Whole-row packed-uint gathers; 2-deep cross-relation software pipeline:
// stage r+1's gathers before consuming r (ping-pong register sets, static names).
#define UNPK(dst, r) \
    dst[0]=q[r][0].x; dst[1]=q[r][0].y; dst[2]=q[r][0].z; dst[3]=q[r][0].w; \
    dst[4]=q[r][1].x; dst[5]=q[r][1].y; dst[6]=q[r][1].z; dst[7]=q[r][1].w; \
    dst[8]=q[r][2].x; dst[9]=q[r][2].y; dst[10]=q[r][2].z; dst[11]=q[r][2].w; \
    dst[12]=q[r][3].x; dst[13]=q[r][3].y; dst[14]=q[r][3].z; dst[15]=q[r][3].w;

__global__ __launch_bounds__(256) void k_aggall(const int* __restrict__ cnt_in,
                                                const int* __restrict__ bucket,
                                                const float* __restrict__ norm_out,
                                                const float* __restrict__ norm_in,
                                                const int* __restrict__ ov_cnt,
                                                const uint2* __restrict__ ovlist,
                                                const unsigned int* __restrict__ xb,
                                                unsigned int* __restrict__ aggh) {
    int w = (blockIdx.x * 256 + threadIdx.x) >> 6;
    if (w >= N_NODES) return;
    int lane = threadIdx.x & 63;
    const unsigned int* tab = xb + lane;
    int nn[R_REL];
    uint4 q[R_REL][4];
#pragma unroll
    for (int r = 0; r < R_REL; r++) {
        int bin = r * N_NODES + w;
        int n = cnt_in[bin];
        nn[r] = n < BCAP ? n : BCAP;
        const uint4* bp = (const uint4*)(bucket + bin * BCAP);
        q[r][0] = bp[0]; q[r][1] = bp[1]; q[r][2] = bp[2]; q[r][3] = bp[3];
    }
    int oc = *ov_cnt;
    if (oc > OVCAP) oc = OVCAP;

    unsigned int slA[BCAP], slB[BCAP];
    unsigned int pA[BCAP], pB[BCAP];
    float cA[BCAP], cB[BCAP];

#define STAGE1(r, sl, cArr, pArr) { const float* nout = norm_out + (r) * N_NODES; \
    _Pragma("unroll") \
    for (int j = 0; j < BCAP; j++) if (j < nn[r]) { cArr[j] = nout[sl[j]]; pArr[j] = tab[sl[j] * 64]; } }

#define CONSUME1(r, cArr, pArr) { float ax = 0.f, ay = 0.f; \
    _Pragma("unroll") \
    for (int j = 0; j < BCAP; j++) if (j < nn[r]) { ax += cArr[j] * bf_lo(pArr[j]); ay += cArr[j] * bf_hi(pArr[j]); } \
    int bin = (r) * N_NODES + w; \
    if (oc > 0) { const float* nout = norm_out + (r) * N_NODES; \
        for (int k = 0; k < oc; k++) { uint2 e = ovlist[k]; \
            if ((int)e.x == bin) { float cc = nout[e.y]; unsigned int pp = tab[e.y * 64]; \
                ax += cc * bf_lo(pp); ay += cc * bf_hi(pp); } } } \
    float ni = norm_in[bin]; \
    aggh[bin * 64 + lane] = ((unsigned int)f2bf(ay * ni) << 16) | f2bf(ax * ni); }

    UNPK(slA, 0); STAGE1(0, slA, cA, pA);
    UNPK(slB, 1); STAGE1(1, slB, cB, pB);
    CONSUME1(0, cA, pA);
    UNPK(slA, 2); STAGE1(2, slA, cA, pA);
    CONSUME1(1, cB, pB);
    CONSUME1(2, cA, pA);
#undef STAGE1
#undef CONSUME1
}

// ---------------- layer-1 GEMM: h1 = relu([A0|A1|A2](N,384) @ W1cat(384,128) + bsum) ----------------
__global__ __launch_bounds__(256) void k_mm1f(const unsigned short* __restrict__ aggh,
                                              const unsigned short* __restrict__ wt_h,
                                              const unsigned short* __restrict__ wt_l,
                                              const float* __restrict__ bsum,
                                              unsigned short* __restrict__ h1h,
                                              unsigned short* __restrict__ h1l,
                                              int M) {
    __shared__ short sA[2048];                 // [4 kg][64 row][8]
    __shared__ short sWh[4096], sWl[4096];     // [4 kg][128 col][8]
    int t = threadIdx.x;
    int row0 = blockIdx.x * 64;
    int wid = t >> 6;
    int lane = t & 63;
    int lr = lane & 15;
    int lkg = lane >> 4;
    int wr = (wid & 1) * 32;
    int wc = (wid >> 1) * 64;

    f32x4 acc[2][4];
#pragma unroll
    for (int i = 0; i < 2; i++)
#pragma unroll
        for (int j = 0; j < 4; j++) acc[i][j] = (f32x4)(0.f);

    int arow = t >> 2;       // 0..63
    int akg = t & 3;         // 0..3

    for (int k0 = 0; k0 < 384; k0 += 32) {
        int rr = k0 >> 7;
        int kk = k0 & 127;
        {
            int gr = row0 + arow;
            int cidx = akg * 64 + arow;
            if (gr < M)
                *(bf16x8*)&sA[cidx * 8] =
                    *(const bf16x8*)&aggh[(rr * N_NODES + gr) * 128 + kk + akg * 8];
            else
                *(bf16x8*)&sA[cidx * 8] = (bf16x8)(short)0;
        }
#pragma unroll
        for (int itr = 0; itr < 2; itr++) {
            int cc = t + itr * 256;       // 0..511
            int col = cc >> 2;            // 0..127
            int kg = cc & 3;
            int go = rr * 16384 + col * 128 + kk + kg * 8;
            int cidx = kg * 128 + col;
            *(bf16x8*)&sWh[cidx * 8] = *(const bf16x8*)&wt_h[go];
            *(bf16x8*)&sWl[cidx * 8] = *(const bf16x8*)&wt_l[go];
        }
        __syncthreads();
        bf16x8 a[2], bh[4], bl[4];
#pragma unroll
        for (int i = 0; i < 2; i++) {
            int cidx = lkg * 64 + wr + i * 16 + lr;
            a[i] = *(const bf16x8*)&sA[cidx * 8];
        }
#pragma unroll
        for (int j = 0; j < 4; j++) {
            int cidx = lkg * 128 + wc + j * 16 + lr;
            bh[j] = *(const bf16x8*)&sWh[cidx * 8];
            bl[j] = *(const bf16x8*)&sWl[cidx * 8];
        }
#pragma unroll
        for (int i = 0; i < 2; i++)
#pragma unroll
            for (int j = 0; j < 4; j++) {
                acc[i][j] = __builtin_amdgcn_mfma_f32_16x16x32_bf16(a[i], bh[j], acc[i][j], 0, 0, 0);
                acc[i][j] = __builtin_amdgcn_mfma_f32_16x16x32_bf16(a[i], bl[j], acc[i][j], 0, 0, 0);
            }
        __syncthreads();
    }
#pragma unroll
    for (int i = 0; i < 2; i++)
#pragma unroll
        for (int q = 0; q < 4; q++) {
            int gr = row0 + wr + i * 16 + lkg * 4 + q;
            if (gr >= M) continue;
#pragma unroll
            for (int j = 0; j < 4; j++) {
                int gc = wc + j * 16 + lr;
                float u = fmaxf(acc[i][j][q] + bsum[gc], 0.f);
                unsigned short h = f2bf(u);
                h1h[gr * 128 + gc] = h;
                h1l[gr * 128 + gc] = f2bf(u - bf2f(h));
            }
        }
}

// ---------------- MFMA split-bf16 GEMM, layer 2 (bf16 out, plane-major, norm folded) ----------------
__global__ __launch_bounds__(256) void k_mm2(const unsigned short* __restrict__ h1h,
                                             const unsigned short* __restrict__ h1l,
                                             const unsigned short* __restrict__ wt_h,
                                             const unsigned short* __restrict__ wt_l,
                                             const float* __restrict__ norm_out,
                                             unsigned short* __restrict__ xwb2, int M) {
    __shared__ short sAh[2048], sAl[2048];
    __shared__ short sWh[6144], sWl[6144];
    int t = threadIdx.x;
    int row0 = blockIdx.x * 64;
    int wid = t >> 6;
    int lane = t & 63;
    int lr = lane & 15;
    int lkg = lane >> 4;
    int wr = (wid & 1) * 32;
    int wc = (wid >> 1) * 96;

    f32x4 acc[2][6];
#pragma unroll
    for (int i = 0; i < 2; i++)
#pragma unroll
        for (int j = 0; j < 6; j++) acc[i][j] = (f32x4)(0.f);

    int arow = t >> 2;
    int akg = t & 3;

    for (int k0 = 0; k0 < 128; k0 += 32) {
        {
            int gr = row0 + arow;
            int cidx = akg * 64 + arow;
            if (gr < M) {
                int go = gr * 128 + k0 + akg * 8;
                *(bf16x8*)&sAh[cidx * 8] = *(const bf16x8*)&h1h[go];
                *(bf16x8*)&sAl[cidx * 8] = *(const bf16x8*)&h1l[go];
            } else {
                *(bf16x8*)&sAh[cidx * 8] = (bf16x8)(short)0;
                *(bf16x8*)&sAl[cidx * 8] = (bf16x8)(short)0;
            }
        }
#pragma unroll
        for (int itr = 0; itr < 3; itr++) {
            int cc = t + itr * 256;       // 0..767
            int col = cc >> 2;
            int kg = cc & 3;
            int go = col * 128 + k0 + kg * 8;
            int cidx = kg * 192 + col;
            *(bf16x8*)&sWh[cidx * 8] = *(const bf16x8*)&wt_h[go];
            *(bf16x8*)&sWl[cidx * 8] = *(const bf16x8*)&wt_l[go];
        }
        __syncthreads();
        bf16x8 ah[2], al[2];
#pragma unroll
        for (int i = 0; i < 2; i++) {
            int cidx = lkg * 64 + wr + i * 16 + lr;
            ah[i] = *(const bf16x8*)&sAh[cidx * 8];
            al[i] = *(const bf16x8*)&sAl[cidx * 8];
        }
#pragma unroll
        for (int j = 0; j < 6; j++) {
            int cidx = lkg * 192 + wc + j * 16 + lr;
            bf16x8 bh = *(const bf16x8*)&sWh[cidx * 8];
            bf16x8 bl = *(const bf16x8*)&sWl[cidx * 8];
#pragma unroll
            for (int i = 0; i < 2; i++) {
                acc[i][j] = __builtin_amdgcn_mfma_f32_16x16x32_bf16(ah[i], bh, acc[i][j], 0, 0, 0);
                acc[i][j] = __builtin_amdgcn_mfma_f32_16x16x32_bf16(ah[i], bl, acc[i][j], 0, 0, 0);
                acc[i][j] = __builtin_amdgcn_mfma_f32_16x16x32_bf16(al[i], bh, acc[i][j], 0, 0, 0);
            }
        }
        __syncthreads();
    }
#pragma unroll
    for (int i = 0; i < 2; i++)
#pragma unroll
        for (int q = 0; q < 4; q++) {
            int gr = row0 + wr + i * 16 + lkg * 4 + q;
            if (gr >= M) continue;
#pragma unroll
            for (int j = 0; j < 6; j++) {
                int gc = wc + j * 16 + lr;
                int rr = gc >> 6;
                int cl = gc & 63;
                float sc = norm_out[rr * N_NODES + gr];
                // plane-major: [r][node][64]
                xwb2[rr * (N_NODES * 64) + gr * 64 + cl] = f2bf(acc[i][j][q] * sc);
            }
        }
}

// ---------------- fused layer-2 aggregation (plane-major, pipelined staging) ----------------
__global__ __launch_bounds__(256) void k_agg64f(const int* __restrict__ cnt_in,
                                                const int* __restrict__ bucket,
                                                const float* __restrict__ norm_in,
                                                const int* __restrict__ ov_cnt,
                                                const uint2* __restrict__ ovlist,
                                                const unsigned short* __restrict__ xwb,
                                                const float* __restrict__ b2,
                                                unsigned short* __restrict__ h2b) {
    int w = (blockIdx.x * 256 + threadIdx.x) >> 6;
    if (w >= N_NODES) return;
    int lane = threadIdx.x & 63;
    float acc = b2[lane] + b2[64 + lane] + b2[128 + lane];
    int oc = *ov_cnt;
    if (oc > OVCAP) oc = OVCAP;
    int nn[R_REL];
    uint4 q[R_REL][4];
#pragma unroll
    for (int r = 0; r < R_REL; r++) {
        int bin = r * N_NODES + w;
        int n = cnt_in[bin];
        nn[r] = n < BCAP ? n : BCAP;
        const uint4* bp = (const uint4*)(bucket + bin * BCAP);
        q[r][0] = bp[0]; q[r][1] = bp[1]; q[r][2] = bp[2]; q[r][3] = bp[3];
    }
    unsigned int slA[BCAP], slB[BCAP];
    unsigned short pvA[BCAP], pvB[BCAP];

#define STAGE2(r, sl, pv) { const unsigned short* tab = xwb + (r) * (N_NODES * 64) + lane; \
    _Pragma("unroll") \
    for (int j = 0; j < BCAP; j++) if (j < nn[r]) pv[j] = tab[sl[j] * 64]; }

#define CONSUME2(r, pv) { float a = 0.f; \
    _Pragma("unroll") \
    for (int j = 0; j < BCAP; j++) if (j < nn[r]) a += bf2f(pv[j]); \
    int bin = (r) * N_NODES + w; \
    if (oc > 0) { const unsigned short* tab = xwb + (r) * (N_NODES * 64) + lane; \
        for (int k = 0; k < oc; k++) { uint2 e = ovlist[k]; \
            if ((int)e.x == bin) a += bf2f(tab[e.y * 64]); } } \
    acc += norm_in[bin] * a; }

    UNPK(slA, 0); STAGE2(0, slA, pvA);
    UNPK(slB, 1); STAGE2(1, slB, pvB);
    CONSUME2(0, pvA);
    UNPK(slA, 2); STAGE2(2, slA, pvA);
    CONSUME2(1, pvB);
    CONSUME2(2, pvA);
#undef STAGE2
#undef CONSUME2
    h2b[w * 64 + lane] = f2bf(acc);
}

// ---------------- predictor (bf16 h2) ----------------
__global__ __launch_bounds__(256) void k_predict(const int* __restrict__ sa,
                                                 const int* __restrict__ sb,
                                                 const int* __restrict__ na,
                                                 const int* __restrict__ nb,
                                                 const unsigned short* __restrict__ h2b,
                                                 float* __restrict__ out) {
    int tid = blockIdx.x * 256 + threadIdx.x;
    int p = tid >> 4;
    if (p >= 2 * E_EDGES) return;
    int lane = tid & 15;
    int ia, ib;
    if (p < E_EDGES) { ia = sa[p]; ib = sb[p]; }
    else             { ia = na[p - E_EDGES]; ib = nb[p - E_EDGES]; }
    uint2 ua = *(const uint2*)&h2b[ia * 64 + lane * 4];
    uint2 ub = *(const uint2*)&h2b[ib * 64 + lane * 4];
    float d = bf_lo(ua.x) * bf_lo(ub.x) + bf_hi(ua.x) * bf_hi(ub.x)
            + bf_lo(ua.y) * bf_lo(ub.y) + bf_hi(ua.y) * bf_hi(ub.y);
    d += __shfl_xor(d, 1);
    d += __shfl_xor(d, 2);
    d += __shfl_xor(d, 4);
    d += __shfl_xor(d, 8);
    if (lane == 0) out[p] = d;
}

// ---------------- launch ----------------

extern "C" void kernel_launch(void* const* d_in, const int* in_sizes, int n_in,
                              void* d_out, int out_size, void* d_ws, size_t ws_size,
                              hipStream_t stream) {
    (void)in_sizes; (void)n_in; (void)out_size; (void)ws_size;
    const float* x       = (const float*)d_in[0];
    const int*   src     = (const int*)d_in[1];
    const int*   dst     = (const int*)d_in[2];
    const int*   neg_src = (const int*)d_in[3];
    const int*   neg_dst = (const int*)d_in[4];
    const float* W1      = (const float*)d_in[5];
    const float* b1      = (const float*)d_in[6];
    const float* W2      = (const float*)d_in[7];
    const float* b2      = (const float*)d_in[8];
    float* out = (float*)d_out;
    float* ws  = (float*)d_ws;

    // float-offset layout (total 19,082,064 floats = 76.3 MB; 96.8 MB proven):
    // 0        : norm_out [150000]   150000: norm_in [150000]
    // 300000   : deg_out int [150000]  450000: cnt_in [150000]  600000: ov_cnt [16]
    // 600016   : ovlist uint2 [4096] = 8192 ints
    // 608208   : bucket int [2.4M]
    // 3008208  : w1t_h [24576] 3032784: w1t_l [24576] 3057360: w2t_h [12288]
    // 3069648  : w2t_l [12288] 3081936: bsum [128]
    // 3082064  : aggh bf16 [3 planes, 9.6M floats]   (alias: xwb2 plane-major 4.8Mf late)
    // 12682064 : h1h [3.2M]                          (alias: h2b 1.6M floats late)
    // 15882064 : h1l [3.2M]                          (alias: xb 3.2M early)
    float* norm_out = ws;
    float* norm_in  = ws + N_SCAN;
    int*   deg_out  = (int*)(ws + 300000);
    int*   cnt_in   = (int*)(ws + 450000);
    int*   ov_cnt   = (int*)(ws + 600000);
    uint2* ovlist   = (uint2*)(ws + 600016);
    int*   bucket   = (int*)(ws + 608208);
    unsigned short* w1t_h = (unsigned short*)(ws + 3008208);
    unsigned short* w1t_l = (unsigned short*)(ws + 3032784);
    unsigned short* w2t_h = (unsigned short*)(ws + 3057360);
    unsigned short* w2t_l = (unsigned short*)(ws + 3069648);
    float* bsum     = ws + 3081936;
    unsigned int*   aggh = (unsigned int*)(ws + 3082064);
    unsigned short* xwb2 = (unsigned short*)(ws + 3082064);
    unsigned short* h1h  = (unsigned short*)(ws + 12682064);
    unsigned short* h2b  = (unsigned short*)(ws + 12682064);
    unsigned short* h1l  = (unsigned short*)(ws + 15882064);
    unsigned int*   xb   = (unsigned int*)(ws + 15882064);

    const int NB_WAVE = (N_NODES * 64 + 255) / 256;      // 12500
    const int NB_MM   = (N_NODES + 63) / 64;             // 782

    // zero counters (deg_out, cnt_in, ov_cnt contiguous) via async memset
    hipMemsetAsync(deg_out, 0, (size_t)300016 * sizeof(int), stream);
    // fused count + bucket-scatter + prep (role-split, 782 groups of 5 blocks)
    k_count_prep<<<782 * 5, 256, 0, stream>>>(src, dst, x, W1, W2, b1,
                                              deg_out, cnt_in, ov_cnt, ovlist, bucket,
                                              xb, w1t_h, w1t_l, w2t_h, w2t_l, bsum);
    k_rednorm<<<(N_SCAN + 255) / 256, 256, 0, stream>>>(deg_out, cnt_in, norm_out, norm_in);

    // ---- layer 1: one aggregation kernel (1 wave/node, pipelined) + one K=384 GEMM ----
    k_aggall<<<NB_WAVE, 256, 0, stream>>>(cnt_in, bucket, norm_out, norm_in,
                                          ov_cnt, ovlist, xb, aggh);
    k_mm1f<<<NB_MM, 256, 0, stream>>>((const unsigned short*)aggh, w1t_h, w1t_l, bsum,
                                      h1h, h1l, N_NODES);

    // ---- layer 2: GEMM [N,128]@[128,192] -> bf16 plane-major, then aggregation ----
    k_mm2<<<NB_MM, 256, 0, stream>>>(h1h, h1l, w2t_h, w2t_l, norm_out, xwb2, N_NODES);
    k_agg64f<<<NB_WAVE, 256, 0, stream>>>(cnt_in, bucket, norm_in, ov_cnt, ovlist,
                                          xwb2, b2, h2b);

    // ---- predictor ----
    k_predict<<<(2 * E_EDGES * 16 + 255) / 256, 256, 0, stream>>>(
        src, dst, neg_src, neg_dst, h2b, out);
}

// Round 12
// 251.139 us; speedup vs baseline: 1.3159x; 1.1144x over previous
//
#include <hip/hip_runtime.h>

#define N_NODES 50000
#define E_EDGES 200000
#define R_REL 3
#define D_IN 128
#define D_HID 128
#define D_OUT 64
#define N_SCAN (R_REL * N_NODES)          // 150000
#define BCAP 16
#define OVCAP 4096

typedef __attribute__((ext_vector_type(8))) short bf16x8;
typedef __attribute__((ext_vector_type(4))) float f32x4;

__device__ inline unsigned short f2bf(float v) {
    union { float f; unsigned int u; } x; x.f = v;
    unsigned int r = x.u + 0x7fffu + ((x.u >> 16) & 1u);
    return (unsigned short)(r >> 16);
}
__device__ inline float bf2f(unsigned short h) {
    union { unsigned int u; float f; } x; x.u = ((unsigned int)h) << 16; return x.f;
}
__device__ inline float bf_lo(unsigned int p) {
    union { unsigned int u; float f; } x; x.u = p << 16; return x.f;
}
__device__ inline float bf_hi(unsigned int p) {
    union { unsigned int u; float f; } x; x.u = p & 0xffff0000u; return x.f;
}

// ---------------- fused count/bucket + prep, role-split blocks ----------------
__global__ __launch_bounds__(256) void k_count_prep(const int* __restrict__ src,
                                                    const int* __restrict__ dst,
                                                    const float* __restrict__ x,
                                                    const float* __restrict__ W1,
                                                    const float* __restrict__ W2,
                                                    const float* __restrict__ b1,
                                                    int* __restrict__ deg_out,
                                                    int* __restrict__ cnt_in,
                                                    int* __restrict__ ov_cnt,
                                                    uint2* __restrict__ ovlist,
                                                    int* __restrict__ bucket,
                                                    unsigned int* __restrict__ xb,
                                                    unsigned short* __restrict__ w1t_h,
                                                    unsigned short* __restrict__ w1t_l,
                                                    unsigned short* __restrict__ w2t_h,
                                                    unsigned short* __restrict__ w2t_l,
                                                    float* __restrict__ bsum) {
    int g = blockIdx.x / 5;
    int m = blockIdx.x % 5;
    int t = threadIdx.x;
    if (m < 3) {
        // ---- edge path: count + bucket scatter ----
        int eb = g * 3 + m;
        int i = eb * 256 + t;
        if (i >= R_REL * E_EDGES) return;
        int r = i / E_EDGES;
        int s = src[i];
        int d = dst[i];
        atomicAdd(&deg_out[r * N_NODES + s], 1);
        int bin = r * N_NODES + d;
        int pos = atomicAdd(&cnt_in[bin], 1);
        if (pos < BCAP) {
            bucket[bin * BCAP + pos] = s;
        } else {
            int oi = atomicAdd(ov_cnt, 1);
            if (oi < OVCAP) {
                uint2 e;
                e.x = (unsigned int)bin;
                e.y = (unsigned int)s;
                ovlist[oi] = e;
            }
        }
    } else {
        // ---- streaming prep path (coalesced: 4 lane-consecutive passes) ----
        int pb = g * 2 + (m - 3);
        int qbase = pb * 1024;
#pragma unroll
        for (int k = 0; k < 4; k++) {
            int q = qbase + k * 256 + t;
            if (q < N_NODES * 32) {
                float4 v = ((const float4*)x)[q];
                uint2 u;
                u.x = ((unsigned int)f2bf(v.y) << 16) | f2bf(v.x);
                u.y = ((unsigned int)f2bf(v.w) << 16) | f2bf(v.z);
                ((uint2*)xb)[q] = u;
            }
        }
        int i = pb * 256 + t;
        if (i < R_REL * D_IN * D_HID) {  // 49152
            int r = i >> 14;
            int kk = (i >> 7) & 127;
            int c = i & 127;
            float v = W1[i];
            unsigned short h = f2bf(v);
            unsigned short l = f2bf(v - bf2f(h));
            int o = r * 16384 + c * 128 + kk;
            w1t_h[o] = h;
            w1t_l[o] = l;
        }
        if (i < R_REL * D_HID * D_OUT) {  // 24576
            int r = i >> 13;
            int kk = (i >> 6) & 127;
            int cl = i & 63;
            float v = W2[i];
            unsigned short h = f2bf(v);
            unsigned short l = f2bf(v - bf2f(h));
            int o = (r * 64 + cl) * 128 + kk;
            w2t_h[o] = h;
            w2t_l[o] = l;
        }
        if (i < 128) bsum[i] = b1[i] + b1[128 + i] + b1[256 + i];
    }
}

// ---------------- layer-1 aggregation (round-9 staged form) + fused norm tables ----------------
#define UNPK(dst, r) \
    dst[0]=q[r][0].x; dst[1]=q[r][0].y; dst[2]=q[r][0].z; dst[3]=q[r][0].w; \
    dst[4]=q[r][1].x; dst[5]=q[r][1].y; dst[6]=q[r][1].z; dst[7]=q[r][1].w; \
    dst[8]=q[r][2].x; dst[9]=q[r][2].y; dst[10]=q[r][2].z; dst[11]=q[r][2].w; \
    dst[12]=q[r][3].x; dst[13]=q[r][3].y; dst[14]=q[r][3].z; dst[15]=q[r][3].w;

__global__ __launch_bounds__(256) void k_aggall(const int* __restrict__ cnt_in,
                                                const int* __restrict__ bucket,
                                                const int* __restrict__ deg_out,
                                                const int* __restrict__ ov_cnt,
                                                const uint2* __restrict__ ovlist,
                                                const unsigned int* __restrict__ xb,
                                                unsigned int* __restrict__ aggh,
                                                float* __restrict__ norm_out,
                                                float* __restrict__ norm_in) {
    int w = (blockIdx.x * 256 + threadIdx.x) >> 6;
    if (w >= N_NODES) return;
    int lane = threadIdx.x & 63;
    const unsigned int* tab = xb + lane;
    int nn[R_REL], nraw[R_REL];
    uint4 q[R_REL][4];
#pragma unroll
    for (int r = 0; r < R_REL; r++) {
        int bin = r * N_NODES + w;
        int n = cnt_in[bin];
        nraw[r] = n;
        nn[r] = n < BCAP ? n : BCAP;
        const uint4* bp = (const uint4*)(bucket + bin * BCAP);
        q[r][0] = bp[0]; q[r][1] = bp[1]; q[r][2] = bp[2]; q[r][3] = bp[3];
    }
    // write norm tables for downstream consumers (mm2, agg64f)
    if (lane < R_REL) {
        int bin = lane * N_NODES + w;
        int nr = lane == 0 ? nraw[0] : (lane == 1 ? nraw[1] : nraw[2]);
        norm_in[bin] = rsqrtf((float)(nr > 1 ? nr : 1));
        int dd = deg_out[bin];
        norm_out[bin] = rsqrtf((float)(dd > 1 ? dd : 1));
    }
    int oc = *ov_cnt;
    if (oc > OVCAP) oc = OVCAP;
#pragma unroll
    for (int r = 0; r < R_REL; r++) {
        const int* dout = deg_out + r * N_NODES;
        unsigned int sl[BCAP];
        UNPK(sl, r);
        int dg[BCAP];
        unsigned int p[BCAP];
        // phase 1: issue all gathers (deg broadcast load + row gather per slot)
#pragma unroll
        for (int j = 0; j < BCAP; j++) {
            if (j < nn[r]) {
                dg[j] = dout[sl[j]];
                p[j] = tab[sl[j] * 64];
            }
        }
        // phase 2: consume
        float ax = 0.f, ay = 0.f;
#pragma unroll
        for (int j = 0; j < BCAP; j++) {
            if (j < nn[r]) {
                float c = rsqrtf((float)(dg[j] > 1 ? dg[j] : 1));
                ax += c * bf_lo(p[j]);
                ay += c * bf_hi(p[j]);
            }
        }
        int bin = r * N_NODES + w;
        if (oc > 0) {
            for (int k = 0; k < oc; k++) {
                uint2 e = ovlist[k];
                if ((int)e.x == bin) {
                    int dd = dout[e.y];
                    float cc = rsqrtf((float)(dd > 1 ? dd : 1));
                    unsigned int pp = tab[e.y * 64];
                    ax += cc * bf_lo(pp);
                    ay += cc * bf_hi(pp);
                }
            }
        }
        float ni = rsqrtf((float)(nraw[r] > 1 ? nraw[r] : 1));
        aggh[bin * 64 + lane] = ((unsigned int)f2bf(ay * ni) << 16) | f2bf(ax * ni);
    }
}

// ---------------- layer-1 GEMM: h1h = bf16(relu([A0|A1|A2](N,384) @ W1cat + bsum)) ----------------
__global__ __launch_bounds__(256) void k_mm1f(const unsigned short* __restrict__ aggh,
                                              const unsigned short* __restrict__ wt_h,
                                              const unsigned short* __restrict__ wt_l,
                                              const float* __restrict__ bsum,
                                              unsigned short* __restrict__ h1h,
                                              int M) {
    __shared__ short sA[2048];                 // [4 kg][64 row][8]
    __shared__ short sWh[4096], sWl[4096];     // [4 kg][128 col][8]
    int t = threadIdx.x;
    int row0 = blockIdx.x * 64;
    int wid = t >> 6;
    int lane = t & 63;
    int lr = lane & 15;
    int lkg = lane >> 4;
    int wr = (wid & 1) * 32;
    int wc = (wid >> 1) * 64;

    f32x4 acc[2][4];
#pragma unroll
    for (int i = 0; i < 2; i++)
#pragma unroll
        for (int j = 0; j < 4; j++) acc[i][j] = (f32x4)(0.f);

    int arow = t >> 2;       // 0..63
    int akg = t & 3;         // 0..3

    for (int k0 = 0; k0 < 384; k0 += 32) {
        int rr = k0 >> 7;
        int kk = k0 & 127;
        {
            int gr = row0 + arow;
            int cidx = akg * 64 + arow;
            if (gr < M)
                *(bf16x8*)&sA[cidx * 8] =
                    *(const bf16x8*)&aggh[(rr * N_NODES + gr) * 128 + kk + akg * 8];
            else
                *(bf16x8*)&sA[cidx * 8] = (bf16x8)(short)0;
        }
#pragma unroll
        for (int itr = 0; itr < 2; itr++) {
            int cc = t + itr * 256;       // 0..511
            int col = cc >> 2;            // 0..127
            int kg = cc & 3;
            int go = rr * 16384 + col * 128 + kk + kg * 8;
            int cidx = kg * 128 + col;
            *(bf16x8*)&sWh[cidx * 8] = *(const bf16x8*)&wt_h[go];
            *(bf16x8*)&sWl[cidx * 8] = *(const bf16x8*)&wt_l[go];
        }
        __syncthreads();
        bf16x8 a[2], bh[4], bl[4];
#pragma unroll
        for (int i = 0; i < 2; i++) {
            int cidx = lkg * 64 + wr + i * 16 + lr;
            a[i] = *(const bf16x8*)&sA[cidx * 8];
        }
#pragma unroll
        for (int j = 0; j < 4; j++) {
            int cidx = lkg * 128 + wc + j * 16 + lr;
            bh[j] = *(const bf16x8*)&sWh[cidx * 8];
            bl[j] = *(const bf16x8*)&sWl[cidx * 8];
        }
#pragma unroll
        for (int i = 0; i < 2; i++)
#pragma unroll
            for (int j = 0; j < 4; j++) {
                acc[i][j] = __builtin_amdgcn_mfma_f32_16x16x32_bf16(a[i], bh[j], acc[i][j], 0, 0, 0);
                acc[i][j] = __builtin_amdgcn_mfma_f32_16x16x32_bf16(a[i], bl[j], acc[i][j], 0, 0, 0);
            }
        __syncthreads();
    }
#pragma unroll
    for (int i = 0; i < 2; i++)
#pragma unroll
        for (int q = 0; q < 4; q++) {
            int gr = row0 + wr + i * 16 + lkg * 4 + q;
            if (gr >= M) continue;
#pragma unroll
            for (int j = 0; j < 4; j++) {
                int gc = wc + j * 16 + lr;
                float u = fmaxf(acc[i][j][q] + bsum[gc], 0.f);
                h1h[gr * 128 + gc] = f2bf(u);
            }
        }
}

// ---------------- layer-2 GEMM (h1 hi-only, 2 MFMA, bf16 out, norm_out folded) ----------------
__global__ __launch_bounds__(256) void k_mm2(const unsigned short* __restrict__ h1h,
                                             const unsigned short* __restrict__ wt_h,
                                             const unsigned short* __restrict__ wt_l,
                                             const float* __restrict__ norm_out,
                                             unsigned short* __restrict__ xwb2, int M) {
    __shared__ short sA[2048];
    __shared__ short sWh[6144], sWl[6144];
    int t = threadIdx.x;
    int row0 = blockIdx.x * 64;
    int wid = t >> 6;
    int lane = t & 63;
    int lr = lane & 15;
    int lkg = lane >> 4;
    int wr = (wid & 1) * 32;
    int wc = (wid >> 1) * 96;

    f32x4 acc[2][6];
#pragma unroll
    for (int i = 0; i < 2; i++)
#pragma unroll
        for (int j = 0; j < 6; j++) acc[i][j] = (f32x4)(0.f);

    int arow = t >> 2;
    int akg = t & 3;

    for (int k0 = 0; k0 < 128; k0 += 32) {
        {
            int gr = row0 + arow;
            int cidx = akg * 64 + arow;
            if (gr < M)
                *(bf16x8*)&sA[cidx * 8] = *(const bf16x8*)&h1h[gr * 128 + k0 + akg * 8];
            else
                *(bf16x8*)&sA[cidx * 8] = (bf16x8)(short)0;
        }
#pragma unroll
        for (int itr = 0; itr < 3; itr++) {
            int cc = t + itr * 256;       // 0..767
            int col = cc >> 2;
            int kg = cc & 3;
            int go = col * 128 + k0 + kg * 8;
            int cidx = kg * 192 + col;
            *(bf16x8*)&sWh[cidx * 8] = *(const bf16x8*)&wt_h[go];
            *(bf16x8*)&sWl[cidx * 8] = *(const bf16x8*)&wt_l[go];
        }
        __syncthreads();
        bf16x8 a[2];
#pragma unroll
        for (int i = 0; i < 2; i++) {
            int cidx = lkg * 64 + wr + i * 16 + lr;
            a[i] = *(const bf16x8*)&sA[cidx * 8];
        }
#pragma unroll
        for (int j = 0; j < 6; j++) {
            int cidx = lkg * 192 + wc + j * 16 + lr;
            bf16x8 bh = *(const bf16x8*)&sWh[cidx * 8];
            bf16x8 bl = *(const bf16x8*)&sWl[cidx * 8];
#pragma unroll
            for (int i = 0; i < 2; i++) {
                acc[i][j] = __builtin_amdgcn_mfma_f32_16x16x32_bf16(a[i], bh, acc[i][j], 0, 0, 0);
                acc[i][j] = __builtin_amdgcn_mfma_f32_16x16x32_bf16(a[i], bl, acc[i][j], 0, 0, 0);
            }
        }
        __syncthreads();
    }
#pragma unroll
    for (int i = 0; i < 2; i++)
#pragma unroll
        for (int q = 0; q < 4; q++) {
            int gr = row0 + wr + i * 16 + lkg * 4 + q;
            if (gr >= M) continue;
#pragma unroll
            for (int j = 0; j < 6; j++) {
                int gc = wc + j * 16 + lr;
                float sc = norm_out[(gc >> 6) * N_NODES + gr];
                xwb2[gr * 192 + gc] = f2bf(acc[i][j][q] * sc);
            }
        }
}

// ---------------- fused layer-2 aggregation (round-9 staged form) ----------------
__global__ __launch_bounds__(256) void k_agg64f(const int* __restrict__ cnt_in,
                                                const int* __restrict__ bucket,
                                                const float* __restrict__ norm_in,
                                                const int* __restrict__ ov_cnt,
                                                const uint2* __restrict__ ovlist,
                                                const unsigned short* __restrict__ xwb,
                                                const float* __restrict__ b2,
                                                unsigned short* __restrict__ h2b) {
    int w = (blockIdx.x * 256 + threadIdx.x) >> 6;
    if (w >= N_NODES) return;
    int lane = threadIdx.x & 63;
    float acc = b2[lane] + b2[64 + lane] + b2[128 + lane];
    int oc = *ov_cnt;
    if (oc > OVCAP) oc = OVCAP;
#pragma unroll
    for (int r = 0; r < R_REL; r++) {
        const unsigned short* tab = xwb + r * 64 + lane;
        int bin = r * N_NODES + w;
        int n = cnt_in[bin];
        const uint4* bp = (const uint4*)(bucket + bin * BCAP);
        uint4 q0 = bp[0], q1 = bp[1], q2 = bp[2], q3 = bp[3];
        unsigned int sl[BCAP] = {q0.x, q0.y, q0.z, q0.w, q1.x, q1.y, q1.z, q1.w,
                                 q2.x, q2.y, q2.z, q2.w, q3.x, q3.y, q3.z, q3.w};
        int nn = n < BCAP ? n : BCAP;
        unsigned short pv[BCAP];
        // phase 1: issue all gathers
#pragma unroll
        for (int j = 0; j < BCAP; j++) {
            if (j < nn) pv[j] = tab[sl[j] * 192];
        }
        // phase 2: consume
        float a = 0.f;
#pragma unroll
        for (int j = 0; j < BCAP; j++) {
            if (j < nn) a += bf2f(pv[j]);
        }
        if (oc > 0) {
            for (int k = 0; k < oc; k++) {
                uint2 e = ovlist[k];
                if ((int)e.x == bin) a += bf2f(tab[e.y * 192]);
            }
        }
        acc += norm_in[bin] * a;
    }
    h2b[w * 64 + lane] = f2bf(acc);
}

// ---------------- predictor (bf16 h2) ----------------
__global__ __launch_bounds__(256) void k_predict(const int* __restrict__ sa,
                                                 const int* __restrict__ sb,
                                                 const int* __restrict__ na,
                                                 const int* __restrict__ nb,
                                                 const unsigned short* __restrict__ h2b,
                                                 float* __restrict__ out) {
    int tid = blockIdx.x * 256 + threadIdx.x;
    int p = tid >> 4;
    if (p >= 2 * E_EDGES) return;
    int lane = tid & 15;
    int ia, ib;
    if (p < E_EDGES) { ia = sa[p]; ib = sb[p]; }
    else             { ia = na[p - E_EDGES]; ib = nb[p - E_EDGES]; }
    uint2 ua = *(const uint2*)&h2b[ia * 64 + lane * 4];
    uint2 ub = *(const uint2*)&h2b[ib * 64 + lane * 4];
    float d = bf_lo(ua.x) * bf_lo(ub.x) + bf_hi(ua.x) * bf_hi(ub.x)
            + bf_lo(ua.y) * bf_lo(ub.y) + bf_hi(ua.y) * bf_hi(ub.y);
    d += __shfl_xor(d, 1);
    d += __shfl_xor(d, 2);
    d += __shfl_xor(d, 4);
    d += __shfl_xor(d, 8);
    if (lane == 0) out[p] = d;
}

// ---------------- launch ----------------

extern "C" void kernel_launch(void* const* d_in, const int* in_sizes, int n_in,
                              void* d_out, int out_size, void* d_ws, size_t ws_size,
                              hipStream_t stream) {
    (void)in_sizes; (void)n_in; (void)out_size; (void)ws_size;
    const float* x       = (const float*)d_in[0];
    const int*   src     = (const int*)d_in[1];
    const int*   dst     = (const int*)d_in[2];
    const int*   neg_src = (const int*)d_in[3];
    const int*   neg_dst = (const int*)d_in[4];
    const float* W1      = (const float*)d_in[5];
    const float* b1      = (const float*)d_in[6];
    const float* W2      = (const float*)d_in[7];
    const float* b2      = (const float*)d_in[8];
    float* out = (float*)d_out;
    float* ws  = (float*)d_ws;

    // float-offset layout (total 19,082,064 floats = 76.3 MB; 96.8 MB proven):
    // 0        : norm_out [150000]   150000: norm_in [150000]
    // 300000   : deg_out int [150000]  450000: cnt_in [150000]  600000: ov_cnt [16]
    // 600016   : ovlist uint2 [4096] = 8192 ints
    // 608208   : bucket int [2.4M]
    // 3008208  : w1t_h [24576] 3032784: w1t_l [24576] 3057360: w2t_h [12288]
    // 3069648  : w2t_l [12288] 3081936: bsum [128]
    // 3082064  : aggh uint [9.6M]      (alias: xwb2 bf16 [9.6M ushort] late)
    // 12682064 : h1h ushort [3.2M floats]  (alias: h2b bf16 late)
    // 15882064 : xb uint [3.2M floats]
    float* norm_out = ws;
    float* norm_in  = ws + N_SCAN;
    int*   deg_out  = (int*)(ws + 300000);
    int*   cnt_in   = (int*)(ws + 450000);
    int*   ov_cnt   = (int*)(ws + 600000);
    uint2* ovlist   = (uint2*)(ws + 600016);
    int*   bucket   = (int*)(ws + 608208);
    unsigned short* w1t_h = (unsigned short*)(ws + 3008208);
    unsigned short* w1t_l = (unsigned short*)(ws + 3032784);
    unsigned short* w2t_h = (unsigned short*)(ws + 3057360);
    unsigned short* w2t_l = (unsigned short*)(ws + 3069648);
    float* bsum     = ws + 3081936;
    unsigned int*   aggh = (unsigned int*)(ws + 3082064);
    unsigned short* xwb2 = (unsigned short*)(ws + 3082064);
    unsigned short* h1h  = (unsigned short*)(ws + 12682064);
    unsigned short* h2b  = (unsigned short*)(ws + 12682064);
    unsigned int*   xb   = (unsigned int*)(ws + 15882064);

    const int NB_WAVE = (N_NODES * 64 + 255) / 256;      // 12500
    const int NB_MM   = (N_NODES + 63) / 64;             // 782

    // zero counters (deg_out, cnt_in, ov_cnt contiguous)
    hipMemsetAsync(deg_out, 0, (size_t)300016 * sizeof(int), stream);
    // fused count + bucket-scatter + prep (role-split, 782 groups of 5 blocks)
    k_count_prep<<<782 * 5, 256, 0, stream>>>(src, dst, x, W1, W2, b1,
                                              deg_out, cnt_in, ov_cnt, ovlist, bucket,
                                              xb, w1t_h, w1t_l, w2t_h, w2t_l, bsum);

    // ---- layer 1: aggregation (+inline norms, writes norm tables) + one K=384 GEMM ----
    k_aggall<<<NB_WAVE, 256, 0, stream>>>(cnt_in, bucket, deg_out, ov_cnt, ovlist,
                                          xb, aggh, norm_out, norm_in);
    k_mm1f<<<NB_MM, 256, 0, stream>>>((const unsigned short*)aggh, w1t_h, w1t_l, bsum,
                                      h1h, N_NODES);

    // ---- layer 2: GEMM [N,128]@[128,192] -> bf16 (norm_out folded), then aggregation ----
    k_mm2<<<NB_MM, 256, 0, stream>>>(h1h, w2t_h, w2t_l, norm_out, xwb2, N_NODES);
    k_agg64f<<<NB_WAVE, 256, 0, stream>>>(cnt_in, bucket, norm_in, ov_cnt, ovlist,
                                          xwb2, b2, h2b);

    // ---- predictor ----
    k_predict<<<(2 * E_EDGES * 16 + 255) / 256, 256, 0, stream>>>(
        src, dst, neg_src, neg_dst, h2b, out);
}

// Round 13
// 239.196 us; speedup vs baseline: 1.3816x; 1.0499x over previous
//
#include <hip/hip_runtime.h>

#define N_NODES 50000
#define E_EDGES 200000
#define R_REL 3
#define D_IN 128
#define D_HID 128
#define D_OUT 64
#define N_SCAN (R_REL * N_NODES)          // 150000
#define BCAP 16
#define OVCAP 4096

typedef __attribute__((ext_vector_type(8))) short bf16x8;
typedef __attribute__((ext_vector_type(4))) float f32x4;

__device__ inline unsigned short f2bf(float v) {
    union { float f; unsigned int u; } x; x.f = v;
    unsigned int r = x.u + 0x7fffu + ((x.u >> 16) & 1u);
    return (unsigned short)(r >> 16);
}
__device__ inline float bf2f(unsigned short h) {
    union { unsigned int u; float f; } x; x.u = ((unsigned int)h) << 16; return x.f;
}
__device__ inline float bf_lo(unsigned int p) {
    union { unsigned int u; float f; } x; x.u = p << 16; return x.f;
}
__device__ inline float bf_hi(unsigned int p) {
    union { unsigned int u; float f; } x; x.u = p & 0xffff0000u; return x.f;
}

// ---------------- fused count/bucket + prep, role-split blocks ----------------
__global__ __launch_bounds__(256) void k_count_prep(const int* __restrict__ src,
                                                    const int* __restrict__ dst,
                                                    const float* __restrict__ x,
                                                    const float* __restrict__ W1,
                                                    const float* __restrict__ W2,
                                                    const float* __restrict__ b1,
                                                    int* __restrict__ deg_out,
                                                    int* __restrict__ cnt_in,
                                                    int* __restrict__ ov_cnt,
                                                    uint2* __restrict__ ovlist,
                                                    int* __restrict__ bucket,
                                                    unsigned int* __restrict__ xb,
                                                    unsigned short* __restrict__ w1t_h,
                                                    unsigned short* __restrict__ w1t_l,
                                                    unsigned short* __restrict__ w2t_h,
                                                    unsigned short* __restrict__ w2t_l,
                                                    float* __restrict__ bsum) {
    int g = blockIdx.x / 5;
    int m = blockIdx.x % 5;
    int t = threadIdx.x;
    if (m < 3) {
        // ---- edge path: count + bucket scatter ----
        int eb = g * 3 + m;
        int i = eb * 256 + t;
        if (i >= R_REL * E_EDGES) return;
        int r = i / E_EDGES;
        int s = src[i];
        int d = dst[i];
        atomicAdd(&deg_out[r * N_NODES + s], 1);
        int bin = r * N_NODES + d;
        int pos = atomicAdd(&cnt_in[bin], 1);
        if (pos < BCAP) {
            bucket[bin * BCAP + pos] = s;
        } else {
            int oi = atomicAdd(ov_cnt, 1);
            if (oi < OVCAP) {
                uint2 e;
                e.x = (unsigned int)bin;
                e.y = (unsigned int)s;
                ovlist[oi] = e;
            }
        }
    } else {
        // ---- streaming prep path (coalesced: 4 lane-consecutive passes) ----
        int pb = g * 2 + (m - 3);
        int qbase = pb * 1024;
#pragma unroll
        for (int k = 0; k < 4; k++) {
            int q = qbase + k * 256 + t;
            if (q < N_NODES * 32) {
                float4 v = ((const float4*)x)[q];
                uint2 u;
                u.x = ((unsigned int)f2bf(v.y) << 16) | f2bf(v.x);
                u.y = ((unsigned int)f2bf(v.w) << 16) | f2bf(v.z);
                ((uint2*)xb)[q] = u;
            }
        }
        int i = pb * 256 + t;
        if (i < R_REL * D_IN * D_HID) {  // 49152
            int r = i >> 14;
            int kk = (i >> 7) & 127;
            int c = i & 127;
            float v = W1[i];
            unsigned short h = f2bf(v);
            unsigned short l = f2bf(v - bf2f(h));
            int o = r * 16384 + c * 128 + kk;
            w1t_h[o] = h;
            w1t_l[o] = l;
        }
        if (i < R_REL * D_HID * D_OUT) {  // 24576
            int r = i >> 13;
            int kk = (i >> 6) & 127;
            int cl = i & 63;
            float v = W2[i];
            unsigned short h = f2bf(v);
            unsigned short l = f2bf(v - bf2f(h));
            int o = (r * 64 + cl) * 128 + kk;
            w2t_h[o] = h;
            w2t_l[o] = l;
        }
        if (i < 128) bsum[i] = b1[i] + b1[128 + i] + b1[256 + i];
    }
}

// ---------------- layer-1 aggregation (staged) + fused norm tables ----------------
#define UNPK(dst, r) \
    dst[0]=q[r][0].x; dst[1]=q[r][0].y; dst[2]=q[r][0].z; dst[3]=q[r][0].w; \
    dst[4]=q[r][1].x; dst[5]=q[r][1].y; dst[6]=q[r][1].z; dst[7]=q[r][1].w; \
    dst[8]=q[r][2].x; dst[9]=q[r][2].y; dst[10]=q[r][2].z; dst[11]=q[r][2].w; \
    dst[12]=q[r][3].x; dst[13]=q[r][3].y; dst[14]=q[r][3].z; dst[15]=q[r][3].w;

__global__ __launch_bounds__(256) void k_aggall(const int* __restrict__ cnt_in,
                                                const int* __restrict__ bucket,
                                                const int* __restrict__ deg_out,
                                                const int* __restrict__ ov_cnt,
                                                const uint2* __restrict__ ovlist,
                                                const unsigned int* __restrict__ xb,
                                                unsigned int* __restrict__ aggh,
                                                float* __restrict__ norm_out,
                                                float* __restrict__ norm_in) {
    int w = (blockIdx.x * 256 + threadIdx.x) >> 6;
    if (w >= N_NODES) return;
    int lane = threadIdx.x & 63;
    const unsigned int* tab = xb + lane;
    int nn[R_REL], nraw[R_REL];
    uint4 q[R_REL][4];
#pragma unroll
    for (int r = 0; r < R_REL; r++) {
        int bin = r * N_NODES + w;
        int n = cnt_in[bin];
        nraw[r] = n;
        nn[r] = n < BCAP ? n : BCAP;
        const uint4* bp = (const uint4*)(bucket + bin * BCAP);
        q[r][0] = bp[0]; q[r][1] = bp[1]; q[r][2] = bp[2]; q[r][3] = bp[3];
    }
    // write norm tables for downstream consumers (mm12, agg64f)
    if (lane < R_REL) {
        int bin = lane * N_NODES + w;
        int nr = lane == 0 ? nraw[0] : (lane == 1 ? nraw[1] : nraw[2]);
        norm_in[bin] = rsqrtf((float)(nr > 1 ? nr : 1));
        int dd = deg_out[bin];
        norm_out[bin] = rsqrtf((float)(dd > 1 ? dd : 1));
    }
    int oc = *ov_cnt;
    if (oc > OVCAP) oc = OVCAP;
#pragma unroll
    for (int r = 0; r < R_REL; r++) {
        const int* dout = deg_out + r * N_NODES;
        unsigned int sl[BCAP];
        UNPK(sl, r);
        int dg[BCAP];
        unsigned int p[BCAP];
        // phase 1: issue all gathers
#pragma unroll
        for (int j = 0; j < BCAP; j++) {
            if (j < nn[r]) {
                dg[j] = dout[sl[j]];
                p[j] = tab[sl[j] * 64];
            }
        }
        // phase 2: consume
        float ax = 0.f, ay = 0.f;
#pragma unroll
        for (int j = 0; j < BCAP; j++) {
            if (j < nn[r]) {
                float c = rsqrtf((float)(dg[j] > 1 ? dg[j] : 1));
                ax += c * bf_lo(p[j]);
                ay += c * bf_hi(p[j]);
            }
        }
        int bin = r * N_NODES + w;
        if (oc > 0) {
            for (int k = 0; k < oc; k++) {
                uint2 e = ovlist[k];
                if ((int)e.x == bin) {
                    int dd = dout[e.y];
                    float cc = rsqrtf((float)(dd > 1 ? dd : 1));
                    unsigned int pp = tab[e.y * 64];
                    ax += cc * bf_lo(pp);
                    ay += cc * bf_hi(pp);
                }
            }
        }
        float ni = rsqrtf((float)(nraw[r] > 1 ? nraw[r] : 1));
        aggh[bin * 64 + lane] = ((unsigned int)f2bf(ay * ni) << 16) | f2bf(ax * ni);
    }
}

// ---------------- fused layer-1+2 GEMM ----------------
// Phase A: h1 = relu([A0|A1|A2](128rows,384) @ W1cat + bsum) -> LDS (bf16, frag layout)
// Phase B: xwb2 = (h1 @ W2cat(128,192)) * norm_out -> global bf16
// 512 threads (8 waves), 128-row tile. LDS 56KB: [sA 8K|sW1h 8K|sW1l 8K|sH 32K],
// phase B overlays [sW2h 12K|sW2l 12K] on the sA/sW1 region.
__global__ __launch_bounds__(512) void k_mm12(const unsigned short* __restrict__ aggh,
                                              const unsigned short* __restrict__ w1t_h,
                                              const unsigned short* __restrict__ w1t_l,
                                              const unsigned short* __restrict__ w2t_h,
                                              const unsigned short* __restrict__ w2t_l,
                                              const float* __restrict__ bsum,
                                              const float* __restrict__ norm_out,
                                              unsigned short* __restrict__ xwb2, int M) {
    __shared__ short smem[28672];     // 56 KB
    short* sA   = smem;               // [4 kg][128 row][8]
    short* sW1h = smem + 4096;        // [4 kg][128 col][8]
    short* sW1l = smem + 8192;
    short* sH   = smem + 12288;       // [16 kg][128 row][8]
    short* sW2h = smem;               // phase B: [4 kg][192 col][8]
    short* sW2l = smem + 6144;

    int t = threadIdx.x;
    int row0 = blockIdx.x * 128;
    int wid = t >> 6;
    int lane = t & 63;
    int lr = lane & 15;
    int lkg = lane >> 4;
    int wr = (wid & 3) * 32;          // 4 row groups
    int wc = (wid >> 2) * 64;         // phase A: 2 col groups
    int arow = t >> 2;                // 0..127
    int akg = t & 3;

    // ---- phase A: K=384 GEMM into acc ----
    f32x4 acc[2][4];
#pragma unroll
    for (int i = 0; i < 2; i++)
#pragma unroll
        for (int j = 0; j < 4; j++) acc[i][j] = (f32x4)(0.f);

    for (int k0 = 0; k0 < 384; k0 += 32) {
        int rr = k0 >> 7;
        int kk = k0 & 127;
        {
            int gr = row0 + arow;
            int cidx = akg * 128 + arow;
            if (gr < M)
                *(bf16x8*)&sA[cidx * 8] =
                    *(const bf16x8*)&aggh[(rr * N_NODES + gr) * 128 + kk + akg * 8];
            else
                *(bf16x8*)&sA[cidx * 8] = (bf16x8)(short)0;
        }
        {
            int col = t >> 2;         // 0..127
            int kg = t & 3;
            int go = rr * 16384 + col * 128 + kk + kg * 8;
            int cidx = kg * 128 + col;
            *(bf16x8*)&sW1h[cidx * 8] = *(const bf16x8*)&w1t_h[go];
            *(bf16x8*)&sW1l[cidx * 8] = *(const bf16x8*)&w1t_l[go];
        }
        __syncthreads();
        bf16x8 a[2], bh[4], bl[4];
#pragma unroll
        for (int i = 0; i < 2; i++)
            a[i] = *(const bf16x8*)&sA[(lkg * 128 + wr + i * 16 + lr) * 8];
#pragma unroll
        for (int j = 0; j < 4; j++) {
            int cidx = lkg * 128 + wc + j * 16 + lr;
            bh[j] = *(const bf16x8*)&sW1h[cidx * 8];
            bl[j] = *(const bf16x8*)&sW1l[cidx * 8];
        }
#pragma unroll
        for (int i = 0; i < 2; i++)
#pragma unroll
            for (int j = 0; j < 4; j++) {
                acc[i][j] = __builtin_amdgcn_mfma_f32_16x16x32_bf16(a[i], bh[j], acc[i][j], 0, 0, 0);
                acc[i][j] = __builtin_amdgcn_mfma_f32_16x16x32_bf16(a[i], bl[j], acc[i][j], 0, 0, 0);
            }
        __syncthreads();
    }

    // ---- epilogue A: relu + bias -> sH (bf16, [kg][row][8] fragment layout) ----
#pragma unroll
    for (int i = 0; i < 2; i++)
#pragma unroll
        for (int qq = 0; qq < 4; qq++) {
            int grl = wr + i * 16 + lkg * 4 + qq;     // local row 0..127
            int gr = row0 + grl;
#pragma unroll
            for (int j = 0; j < 4; j++) {
                int gc = wc + j * 16 + lr;
                float u = (gr < M) ? fmaxf(acc[i][j][qq] + bsum[gc], 0.f) : 0.f;
                sH[((gc >> 3) * 128 + grl) * 8 + (gc & 7)] = (short)f2bf(u);
            }
        }
    __syncthreads();

    // ---- phase B: K=128 GEMM (A from sH) ----
    f32x4 acc2[2][6];
#pragma unroll
    for (int i = 0; i < 2; i++)
#pragma unroll
        for (int j = 0; j < 6; j++) acc2[i][j] = (f32x4)(0.f);
    int wc2 = (wid >> 2) * 96;        // 2 col groups of 96

    for (int k0 = 0; k0 < 128; k0 += 32) {
#pragma unroll
        for (int itr = 0; itr < 2; itr++) {
            int cc = t + itr * 512;   // 0..1023, need 768
            if (cc < 768) {
                int col = cc >> 2;    // 0..191
                int kg = cc & 3;
                int go = col * 128 + k0 + kg * 8;
                int cidx = kg * 192 + col;
                *(bf16x8*)&sW2h[cidx * 8] = *(const bf16x8*)&w2t_h[go];
                *(bf16x8*)&sW2l[cidx * 8] = *(const bf16x8*)&w2t_l[go];
            }
        }
        __syncthreads();
        bf16x8 a[2];
#pragma unroll
        for (int i = 0; i < 2; i++)
            a[i] = *(const bf16x8*)&sH[(((k0 >> 3) + lkg) * 128 + wr + i * 16 + lr) * 8];
#pragma unroll
        for (int j = 0; j < 6; j++) {
            int cidx = lkg * 192 + wc2 + j * 16 + lr;
            bf16x8 bh = *(const bf16x8*)&sW2h[cidx * 8];
            bf16x8 bl = *(const bf16x8*)&sW2l[cidx * 8];
#pragma unroll
            for (int i = 0; i < 2; i++) {
                acc2[i][j] = __builtin_amdgcn_mfma_f32_16x16x32_bf16(a[i], bh, acc2[i][j], 0, 0, 0);
                acc2[i][j] = __builtin_amdgcn_mfma_f32_16x16x32_bf16(a[i], bl, acc2[i][j], 0, 0, 0);
            }
        }
        __syncthreads();
    }

    // ---- epilogue B: scale by norm_out, write xwb2 [node][192] ----
#pragma unroll
    for (int i = 0; i < 2; i++)
#pragma unroll
        for (int qq = 0; qq < 4; qq++) {
            int gr = row0 + wr + i * 16 + lkg * 4 + qq;
            if (gr >= M) continue;
#pragma unroll
            for (int j = 0; j < 6; j++) {
                int gc = wc2 + j * 16 + lr;
                float sc = norm_out[(gc >> 6) * N_NODES + gr];
                xwb2[gr * 192 + gc] = f2bf(acc2[i][j][qq] * sc);
            }
        }
}

// ---------------- fused layer-2 aggregation (staged) ----------------
__global__ __launch_bounds__(256) void k_agg64f(const int* __restrict__ cnt_in,
                                                const int* __restrict__ bucket,
                                                const float* __restrict__ norm_in,
                                                const int* __restrict__ ov_cnt,
                                                const uint2* __restrict__ ovlist,
                                                const unsigned short* __restrict__ xwb,
                                                const float* __restrict__ b2,
                                                unsigned short* __restrict__ h2b) {
    int w = (blockIdx.x * 256 + threadIdx.x) >> 6;
    if (w >= N_NODES) return;
    int lane = threadIdx.x & 63;
    float acc = b2[lane] + b2[64 + lane] + b2[128 + lane];
    int oc = *ov_cnt;
    if (oc > OVCAP) oc = OVCAP;
#pragma unroll
    for (int r = 0; r < R_REL; r++) {
        const unsigned short* tab = xwb + r * 64 + lane;
        int bin = r * N_NODES + w;
        int n = cnt_in[bin];
        const uint4* bp = (const uint4*)(bucket + bin * BCAP);
        uint4 q0 = bp[0], q1 = bp[1], q2 = bp[2], q3 = bp[3];
        unsigned int sl[BCAP] = {q0.x, q0.y, q0.z, q0.w, q1.x, q1.y, q1.z, q1.w,
                                 q2.x, q2.y, q2.z, q2.w, q3.x, q3.y, q3.z, q3.w};
        int nn = n < BCAP ? n : BCAP;
        unsigned short pv[BCAP];
#pragma unroll
        for (int j = 0; j < BCAP; j++) {
            if (j < nn) pv[j] = tab[sl[j] * 192];
        }
        float a = 0.f;
#pragma unroll
        for (int j = 0; j < BCAP; j++) {
            if (j < nn) a += bf2f(pv[j]);
        }
        if (oc > 0) {
            for (int k = 0; k < oc; k++) {
                uint2 e = ovlist[k];
                if ((int)e.x == bin) a += bf2f(tab[e.y * 192]);
            }
        }
        acc += norm_in[bin] * a;
    }
    h2b[w * 64 + lane] = f2bf(acc);
}

// ---------------- predictor (bf16 h2) ----------------
__global__ __launch_bounds__(256) void k_predict(const int* __restrict__ sa,
                                                 const int* __restrict__ sb,
                                                 const int* __restrict__ na,
                                                 const int* __restrict__ nb,
                                                 const unsigned short* __restrict__ h2b,
                                                 float* __restrict__ out) {
    int tid = blockIdx.x * 256 + threadIdx.x;
    int p = tid >> 4;
    if (p >= 2 * E_EDGES) return;
    int lane = tid & 15;
    int ia, ib;
    if (p < E_EDGES) { ia = sa[p]; ib = sb[p]; }
    else             { ia = na[p - E_EDGES]; ib = nb[p - E_EDGES]; }
    uint2 ua = *(const uint2*)&h2b[ia * 64 + lane * 4];
    uint2 ub = *(const uint2*)&h2b[ib * 64 + lane * 4];
    float d = bf_lo(ua.x) * bf_lo(ub.x) + bf_hi(ua.x) * bf_hi(ub.x)
            + bf_lo(ua.y) * bf_lo(ub.y) + bf_hi(ua.y) * bf_hi(ub.y);
    d += __shfl_xor(d, 1);
    d += __shfl_xor(d, 2);
    d += __shfl_xor(d, 4);
    d += __shfl_xor(d, 8);
    if (lane == 0) out[p] = d;
}

// ---------------- launch ----------------

extern "C" void kernel_launch(void* const* d_in, const int* in_sizes, int n_in,
                              void* d_out, int out_size, void* d_ws, size_t ws_size,
                              hipStream_t stream) {
    (void)in_sizes; (void)n_in; (void)out_size; (void)ws_size;
    const float* x       = (const float*)d_in[0];
    const int*   src     = (const int*)d_in[1];
    const int*   dst     = (const int*)d_in[2];
    const int*   neg_src = (const int*)d_in[3];
    const int*   neg_dst = (const int*)d_in[4];
    const float* W1      = (const float*)d_in[5];
    const float* b1      = (const float*)d_in[6];
    const float* W2      = (const float*)d_in[7];
    const float* b2      = (const float*)d_in[8];
    float* out = (float*)d_out;
    float* ws  = (float*)d_ws;

    // float-offset layout (total 19,082,064 floats = 76.3 MB; 96.8 MB proven):
    // 0        : norm_out [150000]   150000: norm_in [150000]
    // 300000   : deg_out int [150000]  450000: cnt_in [150000]  600000: ov_cnt [16]
    // 600016   : ovlist uint2 [4096] = 8192 ints
    // 608208   : bucket int [2.4M]
    // 3008208  : w1t_h [24576] 3032784: w1t_l [24576] 3057360: w2t_h [12288]
    // 3069648  : w2t_l [12288] 3081936: bsum [128]
    // 3082064  : aggh uint [9.6M]      (alias: xwb2 bf16 late)
    // 12682064 : h2b bf16
    // 15882064 : xb uint [3.2M floats]
    float* norm_out = ws;
    float* norm_in  = ws + N_SCAN;
    int*   deg_out  = (int*)(ws + 300000);
    int*   cnt_in   = (int*)(ws + 450000);
    int*   ov_cnt   = (int*)(ws + 600000);
    uint2* ovlist   = (uint2*)(ws + 600016);
    int*   bucket   = (int*)(ws + 608208);
    unsigned short* w1t_h = (unsigned short*)(ws + 3008208);
    unsigned short* w1t_l = (unsigned short*)(ws + 3032784);
    unsigned short* w2t_h = (unsigned short*)(ws + 3057360);
    unsigned short* w2t_l = (unsigned short*)(ws + 3069648);
    float* bsum     = ws + 3081936;
    unsigned int*   aggh = (unsigned int*)(ws + 3082064);
    unsigned short* xwb2 = (unsigned short*)(ws + 3082064);
    unsigned short* h2b  = (unsigned short*)(ws + 12682064);
    unsigned int*   xb   = (unsigned int*)(ws + 15882064);

    const int NB_WAVE = (N_NODES * 64 + 255) / 256;      // 12500
    const int NB_MM12 = (N_NODES + 127) / 128;           // 391

    // zero counters (deg_out, cnt_in, ov_cnt contiguous)
    hipMemsetAsync(deg_out, 0, (size_t)300016 * sizeof(int), stream);
    // fused count + bucket-scatter + prep (role-split, 782 groups of 5 blocks)
    k_count_prep<<<782 * 5, 256, 0, stream>>>(src, dst, x, W1, W2, b1,
                                              deg_out, cnt_in, ov_cnt, ovlist, bucket,
                                              xb, w1t_h, w1t_l, w2t_h, w2t_l, bsum);

    // ---- layer 1: aggregation (+inline norms) ----
    k_aggall<<<NB_WAVE, 256, 0, stream>>>(cnt_in, bucket, deg_out, ov_cnt, ovlist,
                                          xb, aggh, norm_out, norm_in);

    // ---- fused layer-1+2 GEMM (h1 never leaves LDS) ----
    k_mm12<<<NB_MM12, 512, 0, stream>>>((const unsigned short*)aggh,
                                        w1t_h, w1t_l, w2t_h, w2t_l,
                                        bsum, norm_out, xwb2, N_NODES);

    // ---- layer-2 aggregation ----
    k_agg64f<<<NB_WAVE, 256, 0, stream>>>(cnt_in, bucket, norm_in, ov_cnt, ovlist,
                                          xwb2, b2, h2b);

    // ---- predictor ----
    k_predict<<<(2 * E_EDGES * 16 + 255) / 256, 256, 0, stream>>>(
        src, dst, neg_src, neg_dst, h2b, out);
}